// Round 1
// baseline (2973.594 us; speedup 1.0000x reference)
//
#include <hip/hip_runtime.h>
#include <math.h>

#define B_ 64
#define Q_ 900
#define C_ 256
#define T_ 100
#define N_ 100            // min(Q,T)
#define BIGF 1.0e30f

// ---------------------------------------------------------------------------
// Kernel A: per-(b,q) softmax stats: rowmax (f32, exact) and denom =
// sum(exp(x - max)) accumulated in f64. One wave (64 lanes) per row of C=256.
// ---------------------------------------------------------------------------
__global__ __launch_bounds__(256) void hm_softmax_stats(
    const float* __restrict__ logits,   // [B*Q, C]
    float* __restrict__ rowmax,         // [B*Q]
    double* __restrict__ denom)         // [B*Q]
{
    int gtid = blockIdx.x * blockDim.x + threadIdx.x;
    int wave = gtid >> 6;
    int lane = threadIdx.x & 63;
    if (wave >= B_ * Q_) return;

    const float* row = logits + (size_t)wave * C_;
    float v[4];
    float m = -INFINITY;
#pragma unroll
    for (int i = 0; i < 4; ++i) {
        v[i] = row[lane + 64 * i];
        m = fmaxf(m, v[i]);
    }
#pragma unroll
    for (int off = 32; off >= 1; off >>= 1)
        m = fmaxf(m, __shfl_xor(m, off, 64));

    double s = 0.0;
#pragma unroll
    for (int i = 0; i < 4; ++i)
        s += exp((double)v[i] - (double)m);
#pragma unroll
    for (int off = 32; off >= 1; off >>= 1)
        s += __shfl_xor(s, off, 64);

    if (lane == 0) {
        rowmax[wave] = m;
        denom[wave]  = s;
    }
}

// ---------------------------------------------------------------------------
// Kernel B: one thread per (b,q,t) cost entry. All math in f64, rounded once
// to f32 on store (minimizes deviation from the numpy f32 reference).
// ---------------------------------------------------------------------------
__global__ __launch_bounds__(256) void hm_cost(
    const float* __restrict__ logits,   // [B,Q,C]
    const float* __restrict__ pboxes,   // [B,Q,4] cxcywh
    const int*   __restrict__ tlabels,  // [B,T]
    const float* __restrict__ tboxes,   // [B,T,4] cxcywh
    const float* __restrict__ rowmax,   // [B*Q]
    const double* __restrict__ denom,   // [B*Q]
    float* __restrict__ cost)           // [B,Q,T]
{
    int idx = blockIdx.x * blockDim.x + threadIdx.x;
    if (idx >= B_ * Q_ * T_) return;
    int t  = idx % T_;
    int bq = idx / T_;
    int b  = bq / Q_;

    // ---- class cost: -softmax(logits[b,q])[label[b,t]]
    int lab   = tlabels[b * T_ + t];
    float lg  = logits[(size_t)bq * C_ + lab];
    double prob = exp((double)lg - (double)rowmax[bq]) / denom[bq];

    // ---- boxes
    const float* pb = pboxes + (size_t)bq * 4;
    const float* tb = tboxes + ((size_t)b * T_ + t) * 4;
    double pcx = pb[0], pcy = pb[1], pw = pb[2], ph = pb[3];
    double tcx = tb[0], tcy = tb[1], tw = tb[2], th = tb[3];

    // L1 on cxcywh
    double l1 = fabs(pcx - tcx) + fabs(pcy - tcy) + fabs(pw - tw) + fabs(ph - th);

    // GIoU on xyxy
    double px1 = pcx - 0.5 * pw, py1 = pcy - 0.5 * ph;
    double px2 = pcx + 0.5 * pw, py2 = pcy + 0.5 * ph;
    double tx1 = tcx - 0.5 * tw, ty1 = tcy - 0.5 * th;
    double tx2 = tcx + 0.5 * tw, ty2 = tcy + 0.5 * th;

    double area1 = fmax(px2 - px1, 0.0) * fmax(py2 - py1, 0.0);
    double area2 = fmax(tx2 - tx1, 0.0) * fmax(ty2 - ty1, 0.0);

    double iw = fmax(fmin(px2, tx2) - fmax(px1, tx1), 0.0);
    double ih = fmax(fmin(py2, ty2) - fmax(py1, ty1), 0.0);
    double inter = iw * ih;
    double uni = area1 + area2 - inter;
    double iou = inter / fmax(uni, 1e-6);

    double ew = fmax(fmax(px2, tx2) - fmin(px1, tx1), 0.0);
    double eh = fmax(fmax(py2, ty2) - fmin(py1, ty1), 0.0);
    double earea = ew * eh;
    double giou = iou - (earea - uni) / fmax(earea, 1e-6);

    double c = -prob + 5.0 * l1 - 2.0 * giou;
    cost[idx] = (float)c;
}

// ---------------------------------------------------------------------------
// Kernel C: greedy assignment, one block (256 threads) per batch.
// Maintains per-row minima in LDS; after masking column j, only rows whose
// cached argmin == j are rescanned. Tie-breaking matches jnp.argmin flat
// order: strict-less scans keep smallest t within a row; the cross-row
// reduction key (orderable_float(val) << 32 | q) keeps smallest q on ties.
// ---------------------------------------------------------------------------
__device__ inline unsigned int hm_ordf(float v) {
    unsigned int u = __float_as_uint(v);
    return (u & 0x80000000u) ? ~u : (u | 0x80000000u);
}

__global__ __launch_bounds__(256) void hm_greedy(
    const float* __restrict__ cost,     // [B,Q,T] (f32, as written by hm_cost)
    float* __restrict__ out_src,        // [B,N]
    float* __restrict__ out_tgt)        // [B,N]
{
    int b   = blockIdx.x;
    int tid = threadIdx.x;
    int lane = tid & 63;
    int wid  = tid >> 6;
    const float* Cb = cost + (size_t)b * Q_ * T_;

    __shared__ float rowmin[Q_];
    __shared__ short rowarg[Q_];
    __shared__ int   colmask[T_];
    __shared__ unsigned long long waveBest[4];
    __shared__ int   pickedJ;

    for (int t = tid; t < T_; t += 256) colmask[t] = 0;

    // phase 1: per-row minima (first occurrence)
    for (int q = tid; q < Q_; q += 256) {
        const float* row = Cb + q * T_;
        float mv = row[0];
        int   ma = 0;
        for (int t = 1; t < T_; ++t) {
            float v = row[t];
            if (v < mv) { mv = v; ma = t; }
        }
        rowmin[q] = mv;
        rowarg[q] = (short)ma;
    }
    __syncthreads();

    for (int k = 0; k < N_; ++k) {
        // thread-local best over owned rows (ascending q, strict < keeps first)
        float bv = 3.0e38f;
        int   bq = Q_;  // sentinel; every thread owns >=3 rows so this is replaced
        for (int q = tid; q < Q_; q += 256) {
            float v = rowmin[q];
            if (v < bv) { bv = v; bq = q; }
        }
        unsigned long long key =
            ((unsigned long long)hm_ordf(bv) << 32) | (unsigned int)bq;
#pragma unroll
        for (int off = 32; off >= 1; off >>= 1) {
            unsigned long long o = __shfl_xor(key, off, 64);
            if (o < key) key = o;
        }
        if (lane == 0) waveBest[wid] = key;
        __syncthreads();

        if (tid == 0) {
            unsigned long long kbest = waveBest[0];
            for (int w = 1; w < 4; ++w)
                if (waveBest[w] < kbest) kbest = waveBest[w];
            int qi = (int)(kbest & 0xFFFFFFFFull);
            int j  = (int)rowarg[qi];
            out_src[b * N_ + k] = (float)qi;
            out_tgt[b * N_ + k] = (float)j;
            rowmin[qi] = BIGF;   // mask row
            colmask[j] = 1;      // mask column
            pickedJ = j;
        }
        __syncthreads();

        int j = pickedJ;
        // rescan rows whose cached argmin column was just masked
        for (int q = tid; q < Q_; q += 256) {
            if (rowmin[q] < BIGF && (int)rowarg[q] == j) {
                const float* row = Cb + q * T_;
                float mv = BIGF;
                int   ma = 0;
                for (int t = 0; t < T_; ++t) {
                    if (!colmask[t]) {
                        float v = row[t];
                        if (v < mv) { mv = v; ma = t; }
                    }
                }
                rowmin[q] = mv;
                rowarg[q] = (short)ma;
            }
        }
        __syncthreads();
    }
}

// ---------------------------------------------------------------------------
extern "C" void kernel_launch(void* const* d_in, const int* in_sizes, int n_in,
                              void* d_out, int out_size, void* d_ws, size_t ws_size,
                              hipStream_t stream)
{
    const float* pred_logits = (const float*)d_in[0];  // [B,Q,C]
    const float* pred_boxes  = (const float*)d_in[1];  // [B,Q,4]
    const int*   tgt_labels  = (const int*)d_in[2];    // [B,T]
    const float* tgt_boxes   = (const float*)d_in[3];  // [B,T,4]

    float* out_cost = (float*)d_out;                       // [B,Q,T]
    float* out_src  = out_cost + (size_t)B_ * Q_ * T_;     // [B,N]
    float* out_tgt  = out_src  + (size_t)B_ * N_;          // [B,N]

    // workspace: denom (f64) then rowmax (f32)
    double* denom  = (double*)d_ws;
    float*  rowmax = (float*)(denom + (size_t)B_ * Q_);

    // A: softmax stats — one wave per (b,q) row
    {
        int waves  = B_ * Q_;
        int blocks = (waves * 64 + 255) / 256;
        hm_softmax_stats<<<blocks, 256, 0, stream>>>(pred_logits, rowmax, denom);
    }
    // B: cost matrix — one thread per (b,q,t)
    {
        int total  = B_ * Q_ * T_;
        int blocks = (total + 255) / 256;
        hm_cost<<<blocks, 256, 0, stream>>>(pred_logits, pred_boxes, tgt_labels,
                                            tgt_boxes, rowmax, denom, out_cost);
    }
    // C: greedy assignment — one block per batch
    hm_greedy<<<B_, 256, 0, stream>>>(out_cost, out_src, out_tgt);
}

// Round 2
// 2731.619 us; speedup vs baseline: 1.0886x; 1.0886x over previous
//
#include <hip/hip_runtime.h>
#include <math.h>

#define B_ 64
#define Q_ 900
#define C_ 256
#define T_ 100
#define N_ 100            // min(Q,T)
#define BIGF 1.0e30f
#define ROWS_PER_LANE 15  // ceil(900/64)

// ---------------------------------------------------------------------------
// Kernel A: per-(b,q) softmax stats: rowmax (f32, exact) and denom =
// sum(exp(x - max)) accumulated in f64. One wave (64 lanes) per row of C=256.
// ---------------------------------------------------------------------------
__global__ __launch_bounds__(256) void hm_softmax_stats(
    const float* __restrict__ logits,   // [B*Q, C]
    float* __restrict__ rowmax,         // [B*Q]
    double* __restrict__ denom)         // [B*Q]
{
    int gtid = blockIdx.x * blockDim.x + threadIdx.x;
    int wave = gtid >> 6;
    int lane = threadIdx.x & 63;
    if (wave >= B_ * Q_) return;

    const float* row = logits + (size_t)wave * C_;
    float v[4];
    float m = -INFINITY;
#pragma unroll
    for (int i = 0; i < 4; ++i) {
        v[i] = row[lane + 64 * i];
        m = fmaxf(m, v[i]);
    }
#pragma unroll
    for (int off = 32; off >= 1; off >>= 1)
        m = fmaxf(m, __shfl_xor(m, off, 64));

    double s = 0.0;
#pragma unroll
    for (int i = 0; i < 4; ++i)
        s += exp((double)v[i] - (double)m);
#pragma unroll
    for (int off = 32; off >= 1; off >>= 1)
        s += __shfl_xor(s, off, 64);

    if (lane == 0) {
        rowmax[wave] = m;
        denom[wave]  = s;
    }
}

// ---------------------------------------------------------------------------
// Kernel B: one thread per (b,q,t) cost entry. All math in f64, rounded once
// to f32 on store (minimizes deviation from the numpy f32 reference).
// ---------------------------------------------------------------------------
__global__ __launch_bounds__(256) void hm_cost(
    const float* __restrict__ logits,   // [B,Q,C]
    const float* __restrict__ pboxes,   // [B,Q,4] cxcywh
    const int*   __restrict__ tlabels,  // [B,T]
    const float* __restrict__ tboxes,   // [B,T,4] cxcywh
    const float* __restrict__ rowmax,   // [B*Q]
    const double* __restrict__ denom,   // [B*Q]
    float* __restrict__ cost)           // [B,Q,T]
{
    int idx = blockIdx.x * blockDim.x + threadIdx.x;
    if (idx >= B_ * Q_ * T_) return;
    int t  = idx % T_;
    int bq = idx / T_;
    int b  = bq / Q_;

    // ---- class cost: -softmax(logits[b,q])[label[b,t]]
    int lab   = tlabels[b * T_ + t];
    float lg  = logits[(size_t)bq * C_ + lab];
    double prob = exp((double)lg - (double)rowmax[bq]) / denom[bq];

    // ---- boxes
    const float* pb = pboxes + (size_t)bq * 4;
    const float* tb = tboxes + ((size_t)b * T_ + t) * 4;
    double pcx = pb[0], pcy = pb[1], pw = pb[2], ph = pb[3];
    double tcx = tb[0], tcy = tb[1], tw = tb[2], th = tb[3];

    // L1 on cxcywh
    double l1 = fabs(pcx - tcx) + fabs(pcy - tcy) + fabs(pw - tw) + fabs(ph - th);

    // GIoU on xyxy
    double px1 = pcx - 0.5 * pw, py1 = pcy - 0.5 * ph;
    double px2 = pcx + 0.5 * pw, py2 = pcy + 0.5 * ph;
    double tx1 = tcx - 0.5 * tw, ty1 = tcy - 0.5 * th;
    double tx2 = tcx + 0.5 * tw, ty2 = tcy + 0.5 * th;

    double area1 = fmax(px2 - px1, 0.0) * fmax(py2 - py1, 0.0);
    double area2 = fmax(tx2 - tx1, 0.0) * fmax(ty2 - ty1, 0.0);

    double iw = fmax(fmin(px2, tx2) - fmax(px1, tx1), 0.0);
    double ih = fmax(fmin(py2, ty2) - fmax(py1, ty1), 0.0);
    double inter = iw * ih;
    double uni = area1 + area2 - inter;
    double iou = inter / fmax(uni, 1e-6);

    double ew = fmax(fmax(px2, tx2) - fmin(px1, tx1), 0.0);
    double eh = fmax(fmax(py2, ty2) - fmin(py1, ty1), 0.0);
    double earea = ew * eh;
    double giou = iou - (earea - uni) / fmax(earea, 1e-6);

    double c = -prob + 5.0 * l1 - 2.0 * giou;
    cost[idx] = (float)c;
}

// ---------------------------------------------------------------------------
// Kernel C0: initial per-row minima (first occurrence), one thread per (b,q).
// ---------------------------------------------------------------------------
__global__ __launch_bounds__(256) void hm_rowmin_init(
    const float* __restrict__ cost,     // [B*Q, T]
    float* __restrict__ rm,             // [B*Q]
    int*   __restrict__ ra)             // [B*Q]
{
    int idx = blockIdx.x * blockDim.x + threadIdx.x;
    if (idx >= B_ * Q_) return;
    const float* row = cost + (size_t)idx * T_;
    float mv = 3.0e38f;
    int   ma = 0;
#pragma unroll
    for (int t4 = 0; t4 < 25; ++t4) {
        float4 v = *reinterpret_cast<const float4*>(row + 4 * t4);
        if (v.x < mv) { mv = v.x; ma = 4 * t4 + 0; }
        if (v.y < mv) { mv = v.y; ma = 4 * t4 + 1; }
        if (v.z < mv) { mv = v.z; ma = 4 * t4 + 2; }
        if (v.w < mv) { mv = v.w; ma = 4 * t4 + 3; }
    }
    rm[idx] = mv;
    ra[idx] = ma;
}

// ---------------------------------------------------------------------------
// Kernel C: greedy assignment, ONE WAVE per batch. Wave-synchronous: no
// __syncthreads, no LDS. rowmin/rowarg in registers (15 rows/lane, fully
// unrolled -> no scratch). Column mask = two wave-uniform u64 registers.
// Pick = 6-level shfl_xor butterfly on key (ordf(val)<<32 | q<<7 | j), which
// replicates jnp.argmin flat-order tie-breaking (smallest q, then smallest t).
// ---------------------------------------------------------------------------
__device__ inline unsigned int hm_ordf(float v) {
    unsigned int u = __float_as_uint(v);
    return (u & 0x80000000u) ? ~u : (u | 0x80000000u);
}

__global__ __launch_bounds__(64) void hm_greedy_wave(
    const float* __restrict__ cost,     // [B,Q,T]
    const float* __restrict__ rm_ws,    // [B*Q]
    const int*   __restrict__ ra_ws,    // [B*Q]
    float* __restrict__ out_src,        // [B,N]
    float* __restrict__ out_tgt)        // [B,N]
{
    int b = blockIdx.x;
    int l = threadIdx.x;                // 0..63
    const float* Cb = cost + (size_t)b * Q_ * T_;

    float rmin[ROWS_PER_LANE];
    int   rarg[ROWS_PER_LANE];
#pragma unroll
    for (int i = 0; i < ROWS_PER_LANE; ++i) {
        int q = l + 64 * i;
        if (q < Q_) {
            rmin[i] = rm_ws[b * Q_ + q];
            rarg[i] = ra_ws[b * Q_ + q];
        } else {
            rmin[i] = BIGF;
            rarg[i] = 127;
        }
    }

    unsigned long long mask_lo = 0ull, mask_hi = 0ull;  // masked columns

    for (int k = 0; k < N_; ++k) {
        // ---- local best over owned rows (ascending i == ascending q)
        float bv  = 3.0e38f;
        int   bqj = (1023 << 7) | 127;  // sentinel
#pragma unroll
        for (int i = 0; i < ROWS_PER_LANE; ++i) {
            if (rmin[i] < bv) {
                bv  = rmin[i];
                bqj = ((l + 64 * i) << 7) | rarg[i];
            }
        }

        // ---- wave-wide min on 64-bit key; all lanes converge
        unsigned long long key =
            ((unsigned long long)hm_ordf(bv) << 32) | (unsigned int)bqj;
#pragma unroll
        for (int off = 32; off >= 1; off >>= 1) {
            unsigned long long o = __shfl_xor(key, off, 64);
            key = (o < key) ? o : key;
        }
        int qi = (int)((key >> 7) & 1023);
        int j  = (int)(key & 127);

        if (l == 0) {
            out_src[b * N_ + k] = (float)qi;
            out_tgt[b * N_ + k] = (float)j;
        }

        // ---- mask column j (wave-uniform registers) and row qi
        if (j < 64) mask_lo |= 1ull << j;
        else        mask_hi |= 1ull << (j - 64);
#pragma unroll
        for (int i = 0; i < ROWS_PER_LANE; ++i)
            if (l + 64 * i == qi) rmin[i] = BIGF;

        // ---- rescan rows whose cached argmin column just got masked
#pragma unroll
        for (int i = 0; i < ROWS_PER_LANE; ++i) {
            if (rarg[i] == j && rmin[i] < 1e29f) {
                const float* row = Cb + (size_t)(l + 64 * i) * T_;
                float mv = 3.0e38f;
                int   ma = 0;
#pragma unroll
                for (int t4 = 0; t4 < 25; ++t4) {
                    float4 v = *reinterpret_cast<const float4*>(row + 4 * t4);
                    {
                        int t = 4 * t4 + 0;
                        bool msk = (t < 64) ? ((mask_lo >> t) & 1ull)
                                            : ((mask_hi >> (t - 64)) & 1ull);
                        float x = msk ? BIGF : v.x;
                        if (x < mv) { mv = x; ma = t; }
                    }
                    {
                        int t = 4 * t4 + 1;
                        bool msk = (t < 64) ? ((mask_lo >> t) & 1ull)
                                            : ((mask_hi >> (t - 64)) & 1ull);
                        float x = msk ? BIGF : v.y;
                        if (x < mv) { mv = x; ma = t; }
                    }
                    {
                        int t = 4 * t4 + 2;
                        bool msk = (t < 64) ? ((mask_lo >> t) & 1ull)
                                            : ((mask_hi >> (t - 64)) & 1ull);
                        float x = msk ? BIGF : v.z;
                        if (x < mv) { mv = x; ma = t; }
                    }
                    {
                        int t = 4 * t4 + 3;
                        bool msk = (t < 64) ? ((mask_lo >> t) & 1ull)
                                            : ((mask_hi >> (t - 64)) & 1ull);
                        float x = msk ? BIGF : v.w;
                        if (x < mv) { mv = x; ma = t; }
                    }
                }
                rmin[i] = mv;
                rarg[i] = ma;
            }
        }
    }
}

// ---------------------------------------------------------------------------
extern "C" void kernel_launch(void* const* d_in, const int* in_sizes, int n_in,
                              void* d_out, int out_size, void* d_ws, size_t ws_size,
                              hipStream_t stream)
{
    const float* pred_logits = (const float*)d_in[0];  // [B,Q,C]
    const float* pred_boxes  = (const float*)d_in[1];  // [B,Q,4]
    const int*   tgt_labels  = (const int*)d_in[2];    // [B,T]
    const float* tgt_boxes   = (const float*)d_in[3];  // [B,T,4]

    float* out_cost = (float*)d_out;                       // [B,Q,T]
    float* out_src  = out_cost + (size_t)B_ * Q_ * T_;     // [B,N]
    float* out_tgt  = out_src  + (size_t)B_ * N_;          // [B,N]

    // workspace layout
    double* denom  = (double*)d_ws;                        // [B*Q] f64
    float*  rowmax = (float*)(denom + (size_t)B_ * Q_);    // [B*Q] f32
    float*  rm_ws  = rowmax + (size_t)B_ * Q_;             // [B*Q] f32
    int*    ra_ws  = (int*)(rm_ws + (size_t)B_ * Q_);      // [B*Q] i32

    // A: softmax stats — one wave per (b,q) row
    {
        int waves  = B_ * Q_;
        int blocks = (waves * 64 + 255) / 256;
        hm_softmax_stats<<<blocks, 256, 0, stream>>>(pred_logits, rowmax, denom);
    }
    // B: cost matrix — one thread per (b,q,t)
    {
        int total  = B_ * Q_ * T_;
        int blocks = (total + 255) / 256;
        hm_cost<<<blocks, 256, 0, stream>>>(pred_logits, pred_boxes, tgt_labels,
                                            tgt_boxes, rowmax, denom, out_cost);
    }
    // C0: initial row minima — one thread per (b,q)
    {
        int total  = B_ * Q_;
        int blocks = (total + 255) / 256;
        hm_rowmin_init<<<blocks, 256, 0, stream>>>(out_cost, rm_ws, ra_ws);
    }
    // C: greedy assignment — one wave per batch, wave-synchronous
    hm_greedy_wave<<<B_, 64, 0, stream>>>(out_cost, rm_ws, ra_ws, out_src, out_tgt);
}

// Round 3
// 139.623 us; speedup vs baseline: 21.2973x; 19.5642x over previous
//
#include <hip/hip_runtime.h>
#include <math.h>

#define B_ 64
#define Q_ 900
#define C_ 256
#define T_ 100
#define N_ 100            // min(Q,T)
#define BIGF 1.0e30f
#define ROWS_PER_LANE 15  // ceil(900/64)

// ---------------------------------------------------------------------------
// Kernel A: per-(b,q) softmax stats: rowmax (f32, exact) and denom =
// sum(exp(x - max)) accumulated in f64. One wave (64 lanes) per row of C=256.
// ---------------------------------------------------------------------------
__global__ __launch_bounds__(256) void hm_softmax_stats(
    const float* __restrict__ logits,   // [B*Q, C]
    float* __restrict__ rowmax,         // [B*Q]
    double* __restrict__ denom)         // [B*Q]
{
    int gtid = blockIdx.x * blockDim.x + threadIdx.x;
    int wave = gtid >> 6;
    int lane = threadIdx.x & 63;
    if (wave >= B_ * Q_) return;

    const float* row = logits + (size_t)wave * C_;
    float v[4];
    float m = -INFINITY;
#pragma unroll
    for (int i = 0; i < 4; ++i) {
        v[i] = row[lane + 64 * i];
        m = fmaxf(m, v[i]);
    }
#pragma unroll
    for (int off = 32; off >= 1; off >>= 1)
        m = fmaxf(m, __shfl_xor(m, off, 64));

    double s = 0.0;
#pragma unroll
    for (int i = 0; i < 4; ++i)
        s += exp((double)v[i] - (double)m);
#pragma unroll
    for (int off = 32; off >= 1; off >>= 1)
        s += __shfl_xor(s, off, 64);

    if (lane == 0) {
        rowmax[wave] = m;
        denom[wave]  = s;
    }
}

// ---------------------------------------------------------------------------
// Kernel B: one thread per (b,q,t) cost entry. All math in f64, rounded once
// to f32 on store (minimizes deviation from the numpy f32 reference).
// ---------------------------------------------------------------------------
__global__ __launch_bounds__(256) void hm_cost(
    const float* __restrict__ logits,   // [B,Q,C]
    const float* __restrict__ pboxes,   // [B,Q,4] cxcywh
    const int*   __restrict__ tlabels,  // [B,T]
    const float* __restrict__ tboxes,   // [B,T,4] cxcywh
    const float* __restrict__ rowmax,   // [B*Q]
    const double* __restrict__ denom,   // [B*Q]
    float* __restrict__ cost)           // [B,Q,T]
{
    int idx = blockIdx.x * blockDim.x + threadIdx.x;
    if (idx >= B_ * Q_ * T_) return;
    int t  = idx % T_;
    int bq = idx / T_;
    int b  = bq / Q_;

    // ---- class cost: -softmax(logits[b,q])[label[b,t]]
    int lab   = tlabels[b * T_ + t];
    float lg  = logits[(size_t)bq * C_ + lab];
    double prob = exp((double)lg - (double)rowmax[bq]) / denom[bq];

    // ---- boxes
    const float* pb = pboxes + (size_t)bq * 4;
    const float* tb = tboxes + ((size_t)b * T_ + t) * 4;
    double pcx = pb[0], pcy = pb[1], pw = pb[2], ph = pb[3];
    double tcx = tb[0], tcy = tb[1], tw = tb[2], th = tb[3];

    // L1 on cxcywh
    double l1 = fabs(pcx - tcx) + fabs(pcy - tcy) + fabs(pw - tw) + fabs(ph - th);

    // GIoU on xyxy
    double px1 = pcx - 0.5 * pw, py1 = pcy - 0.5 * ph;
    double px2 = pcx + 0.5 * pw, py2 = pcy + 0.5 * ph;
    double tx1 = tcx - 0.5 * tw, ty1 = tcy - 0.5 * th;
    double tx2 = tcx + 0.5 * tw, ty2 = tcy + 0.5 * th;

    double area1 = fmax(px2 - px1, 0.0) * fmax(py2 - py1, 0.0);
    double area2 = fmax(tx2 - tx1, 0.0) * fmax(ty2 - ty1, 0.0);

    double iw = fmax(fmin(px2, tx2) - fmax(px1, tx1), 0.0);
    double ih = fmax(fmin(py2, ty2) - fmax(py1, ty1), 0.0);
    double inter = iw * ih;
    double uni = area1 + area2 - inter;
    double iou = inter / fmax(uni, 1e-6);

    double ew = fmax(fmax(px2, tx2) - fmin(px1, tx1), 0.0);
    double eh = fmax(fmax(py2, ty2) - fmin(py1, ty1), 0.0);
    double earea = ew * eh;
    double giou = iou - (earea - uni) / fmax(earea, 1e-6);

    double c = -prob + 5.0 * l1 - 2.0 * giou;
    cost[idx] = (float)c;
}

// ---------------------------------------------------------------------------
// Kernel C0: initial per-COLUMN minima (smallest row on ties), one thread per
// (b,t). Loads coalesced across t.
// ---------------------------------------------------------------------------
__global__ __launch_bounds__(256) void hm_colmin_init(
    const float* __restrict__ cost,     // [B,Q,T]
    float* __restrict__ cm,             // [B*T]
    int*   __restrict__ ca)             // [B*T]
{
    int idx = blockIdx.x * blockDim.x + threadIdx.x;
    if (idx >= B_ * T_) return;
    int b = idx / T_;
    int t = idx % T_;
    const float* Cb = cost + (size_t)b * Q_ * T_;
    float mv = BIGF;
    int   ma = 0;
    for (int q = 0; q < Q_; ++q) {
        float v = Cb[(size_t)q * T_ + t];
        if (v < mv) { mv = v; ma = q; }   // strict < keeps smallest q
    }
    cm[idx] = mv;
    ca[idx] = ma;
}

// ---------------------------------------------------------------------------
// Kernel C: greedy assignment, ONE WAVE per batch, column-min maintenance.
// Each lane owns <=2 columns (t=l and t=64+l). Removing a column deactivates
// an entry; removing a row invalidates only columns whose cached argmin row
// was that row (expected ~0.1/pick) -> wave-parallel column rescan.
// Tie-breaking replicates jnp.argmin flat order via key ordf(v)<<32|q<<7|t.
// ---------------------------------------------------------------------------
__device__ inline unsigned int hm_ordf(float v) {
    unsigned int u = __float_as_uint(v);
    return (u & 0x80000000u) ? ~u : (u | 0x80000000u);
}
__device__ inline float hm_unordf(unsigned int e) {
    unsigned int u = (e & 0x80000000u) ? (e & 0x7FFFFFFFu) : ~e;
    return __uint_as_float(u);
}

__global__ __launch_bounds__(64) void hm_greedy_col(
    const float* __restrict__ cost,     // [B,Q,T]
    const float* __restrict__ cm_ws,    // [B*T]
    const int*   __restrict__ ca_ws,    // [B*T]
    float* __restrict__ out_src,        // [B,N]
    float* __restrict__ out_tgt)        // [B,N]
{
    int b = blockIdx.x;
    int l = threadIdx.x;                // 0..63
    const float* Cb = cost + (size_t)b * Q_ * T_;

    // two column entries per lane: t0 = l, t1 = 64 + l (valid if < T_)
    int   t0 = l, t1 = 64 + l;
    bool  act0 = true;
    bool  act1 = (t1 < T_);
    float cmin0 = cm_ws[b * T_ + t0];
    int   carg0 = ca_ws[b * T_ + t0];
    float cmin1 = act1 ? cm_ws[b * T_ + t1] : BIGF;
    int   carg1 = act1 ? ca_ws[b * T_ + t1] : 0;

    unsigned removed = 0u;  // bit i => row (l + 64*i) removed

    for (int k = 0; k < N_; ++k) {
        // ---- global argmin over active columns
        float v0 = act0 ? cmin0 : BIGF;
        float v1 = act1 ? cmin1 : BIGF;
        unsigned long long k0 =
            ((unsigned long long)hm_ordf(v0) << 32) |
            ((unsigned)carg0 << 7) | (unsigned)t0;
        unsigned long long k1 =
            ((unsigned long long)hm_ordf(v1) << 32) |
            ((unsigned)carg1 << 7) | (unsigned)t1;
        unsigned long long key = (k1 < k0) ? k1 : k0;
#pragma unroll
        for (int off = 32; off >= 1; off >>= 1) {
            unsigned long long o = __shfl_xor(key, off, 64);
            key = (o < key) ? o : key;
        }
        int q = (int)((key >> 7) & 1023);
        int t = (int)(key & 127);

        if (l == 0) {
            out_src[b * N_ + k] = (float)q;
            out_tgt[b * N_ + k] = (float)t;
        }

        // ---- remove column t and row q
        if (t0 == t) act0 = false;
        if (t1 == t) act1 = false;
        if ((q & 63) == l) removed |= 1u << (q >> 6);

        // ---- columns whose cached argmin row just died need rescan
        unsigned long long bal0 = __ballot(act0 && carg0 == q);
        unsigned long long bal1 = __ballot(act1 && carg1 == q);

        while (bal0 | bal1) {
            int tc, owner_entry, owner_lane;
            if (bal0) {
                int p = __ffsll((unsigned long long)bal0) - 1;
                bal0 &= bal0 - 1;
                tc = p; owner_entry = 0; owner_lane = p;
            } else {
                int p = __ffsll((unsigned long long)bal1) - 1;
                bal1 &= bal1 - 1;
                tc = 64 + p; owner_entry = 1; owner_lane = p;
            }
            // wave-parallel rescan of column tc
            unsigned long long bk = ~0ull;
#pragma unroll
            for (int i = 0; i < ROWS_PER_LANE; ++i) {
                int r = l + 64 * i;
                bool ok = (r < Q_) && !((removed >> i) & 1u);
                float v = ok ? Cb[(size_t)r * T_ + tc] : BIGF;
                unsigned long long kk =
                    ((unsigned long long)hm_ordf(v) << 32) | (unsigned)r;
                bk = (kk < bk) ? kk : bk;
            }
#pragma unroll
            for (int off = 32; off >= 1; off >>= 1) {
                unsigned long long o = __shfl_xor(bk, off, 64);
                bk = (o < bk) ? o : bk;
            }
            float nv = hm_unordf((unsigned int)(bk >> 32));
            int   nr = (int)(bk & 0x3FF);
            if (owner_entry == 0) {
                if (l == owner_lane) { cmin0 = nv; carg0 = nr; }
            } else {
                if (l == owner_lane) { cmin1 = nv; carg1 = nr; }
            }
        }
    }
}

// ---------------------------------------------------------------------------
extern "C" void kernel_launch(void* const* d_in, const int* in_sizes, int n_in,
                              void* d_out, int out_size, void* d_ws, size_t ws_size,
                              hipStream_t stream)
{
    const float* pred_logits = (const float*)d_in[0];  // [B,Q,C]
    const float* pred_boxes  = (const float*)d_in[1];  // [B,Q,4]
    const int*   tgt_labels  = (const int*)d_in[2];    // [B,T]
    const float* tgt_boxes   = (const float*)d_in[3];  // [B,T,4]

    float* out_cost = (float*)d_out;                       // [B,Q,T]
    float* out_src  = out_cost + (size_t)B_ * Q_ * T_;     // [B,N]
    float* out_tgt  = out_src  + (size_t)B_ * N_;          // [B,N]

    // workspace layout
    double* denom  = (double*)d_ws;                        // [B*Q] f64
    float*  rowmax = (float*)(denom + (size_t)B_ * Q_);    // [B*Q] f32
    float*  cm_ws  = rowmax + (size_t)B_ * Q_;             // [B*T] f32
    int*    ca_ws  = (int*)(cm_ws + (size_t)B_ * T_);      // [B*T] i32

    // A: softmax stats — one wave per (b,q) row
    {
        int waves  = B_ * Q_;
        int blocks = (waves * 64 + 255) / 256;
        hm_softmax_stats<<<blocks, 256, 0, stream>>>(pred_logits, rowmax, denom);
    }
    // B: cost matrix — one thread per (b,q,t)
    {
        int total  = B_ * Q_ * T_;
        int blocks = (total + 255) / 256;
        hm_cost<<<blocks, 256, 0, stream>>>(pred_logits, pred_boxes, tgt_labels,
                                            tgt_boxes, rowmax, denom, out_cost);
    }
    // C0: initial column minima — one thread per (b,t), coalesced over t
    {
        int total  = B_ * T_;
        int blocks = (total + 255) / 256;
        hm_colmin_init<<<blocks, 256, 0, stream>>>(out_cost, cm_ws, ca_ws);
    }
    // C: greedy assignment — one wave per batch, column-min maintenance
    hm_greedy_col<<<B_, 64, 0, stream>>>(out_cost, cm_ws, ca_ws, out_src, out_tgt);
}

// Round 4
// 134.701 us; speedup vs baseline: 22.0755x; 1.0365x over previous
//
#include <hip/hip_runtime.h>
#include <math.h>

#define B_ 64
#define Q_ 900
#define C_ 256
#define T_ 100
#define N_ 100            // min(Q,T)
#define BIGF 1.0e30f
#define ROWS_PER_LANE 15  // ceil(900/64)

typedef unsigned long long ull;

// ---------------------------------------------------------------------------
// Fused cost kernel: one WAVE per (b,q) row. Computes softmax stats with the
// EXACT same load mapping and reduction order as the previous hm_softmax_stats
// (bit-identical m and denom), stages the 256 f64 exp values in LDS, then each
// lane produces cost entries for t = lane and t = 64+lane. All box math in
// f64, identical expression order to the previous hm_cost -> cost matrix is
// bit-identical to rounds 1-3 (which passed with 288x margin).
// ---------------------------------------------------------------------------
__global__ __launch_bounds__(256) void hm_cost_fused(
    const float* __restrict__ logits,   // [B,Q,C]
    const float* __restrict__ pboxes,   // [B,Q,4] cxcywh
    const int*   __restrict__ tlabels,  // [B,T]
    const float* __restrict__ tboxes,   // [B,T,4] cxcywh
    float* __restrict__ cost)           // [B,Q,T]
{
    int gtid = blockIdx.x * blockDim.x + threadIdx.x;
    int bq   = gtid >> 6;               // wave id == (b,q)
    int lane = threadIdx.x & 63;
    int wid  = threadIdx.x >> 6;        // 0..3
    if (bq >= B_ * Q_) return;
    int b = bq / Q_;

    __shared__ double s_exp[4][C_];     // 8 KB

    // ---- softmax stats (identical to old hm_softmax_stats)
    const float* row = logits + (size_t)bq * C_;
    float v[4];
    float m = -INFINITY;
#pragma unroll
    for (int i = 0; i < 4; ++i) {
        v[i] = row[lane + 64 * i];
        m = fmaxf(m, v[i]);
    }
#pragma unroll
    for (int off = 32; off >= 1; off >>= 1)
        m = fmaxf(m, __shfl_xor(m, off, 64));

    double e[4];
    double s = 0.0;
#pragma unroll
    for (int i = 0; i < 4; ++i) {
        e[i] = exp((double)v[i] - (double)m);
        s += e[i];
    }
#pragma unroll
    for (int off = 32; off >= 1; off >>= 1)
        s += __shfl_xor(s, off, 64);

#pragma unroll
    for (int i = 0; i < 4; ++i)
        s_exp[wid][lane + 64 * i] = e[i];

    // ---- per-target cost entries (identical math to old hm_cost)
    const float* pb = pboxes + (size_t)bq * 4;
    double pcx = pb[0], pcy = pb[1], pw = pb[2], ph = pb[3];

    double px1 = pcx - 0.5 * pw, py1 = pcy - 0.5 * ph;
    double px2 = pcx + 0.5 * pw, py2 = pcy + 0.5 * ph;
    double area1 = fmax(px2 - px1, 0.0) * fmax(py2 - py1, 0.0);

#pragma unroll
    for (int e2 = 0; e2 < 2; ++e2) {
        int t = lane + 64 * e2;
        if (t < T_) {
            int lab = tlabels[b * T_ + t];
            double prob = s_exp[wid][lab] / s;   // == exp(lg - m) / denom, bit-identical

            const float* tb = tboxes + ((size_t)b * T_ + t) * 4;
            double tcx = tb[0], tcy = tb[1], tw = tb[2], th = tb[3];

            double l1 = fabs(pcx - tcx) + fabs(pcy - tcy) + fabs(pw - tw) + fabs(ph - th);

            double tx1 = tcx - 0.5 * tw, ty1 = tcy - 0.5 * th;
            double tx2 = tcx + 0.5 * tw, ty2 = tcy + 0.5 * th;

            double area2 = fmax(tx2 - tx1, 0.0) * fmax(ty2 - ty1, 0.0);

            double iw = fmax(fmin(px2, tx2) - fmax(px1, tx1), 0.0);
            double ih = fmax(fmin(py2, ty2) - fmax(py1, ty1), 0.0);
            double inter = iw * ih;
            double uni = area1 + area2 - inter;
            double iou = inter / fmax(uni, 1e-6);

            double ew = fmax(fmax(px2, tx2) - fmin(px1, tx1), 0.0);
            double eh = fmax(fmax(py2, ty2) - fmin(py1, ty1), 0.0);
            double earea = ew * eh;
            double giou = iou - (earea - uni) / fmax(earea, 1e-6);

            double c = -prob + 5.0 * l1 - 2.0 * giou;
            cost[(size_t)bq * T_ + t] = (float)c;
        }
    }
}

// ---------------------------------------------------------------------------
// Key helpers: order-preserving f32 <-> u32 map; min over (value, row/flat).
// ---------------------------------------------------------------------------
__device__ inline unsigned int hm_ordf(float v) {
    unsigned int u = __float_as_uint(v);
    return (u & 0x80000000u) ? ~u : (u | 0x80000000u);
}
__device__ inline float hm_unordf(unsigned int e) {
    unsigned int u = (e & 0x80000000u) ? (e & 0x7FFFFFFFu) : ~e;
    return __uint_as_float(u);
}

// ---------------------------------------------------------------------------
// Column-min init: one WAVE per (b,t). Lane l reduces rows l, l+64, ...;
// 6-level butterfly on key ordf(v)<<32 | r gives min value with smallest row
// on ties (exact same result as an ascending strict-< scan).
// ---------------------------------------------------------------------------
__global__ __launch_bounds__(256) void hm_colmin_wave(
    const float* __restrict__ cost,     // [B,Q,T]
    float* __restrict__ cm,             // [B*T]
    int*   __restrict__ ca)             // [B*T]
{
    int gtid = blockIdx.x * blockDim.x + threadIdx.x;
    int w = gtid >> 6;                  // (b,t) index
    int l = threadIdx.x & 63;
    if (w >= B_ * T_) return;
    int b = w / T_;
    int t = w % T_;
    const float* Cb = cost + (size_t)b * Q_ * T_;

    ull bk = ~0ull;
#pragma unroll
    for (int i = 0; i < ROWS_PER_LANE; ++i) {
        int r = l + 64 * i;
        float v = (r < Q_) ? Cb[(size_t)r * T_ + t] : BIGF;
        ull kk = ((ull)hm_ordf(v) << 32) | (unsigned)r;
        bk = (kk < bk) ? kk : bk;
    }
#pragma unroll
    for (int off = 32; off >= 1; off >>= 1) {
        ull o = __shfl_xor(bk, off, 64);
        bk = (o < bk) ? o : bk;
    }
    if (l == 0) {
        cm[w] = hm_unordf((unsigned int)(bk >> 32));
        ca[w] = (int)(bk & 1023u);
    }
}

// ---------------------------------------------------------------------------
// Greedy assignment: ONE WAVE per batch, column-min maintenance, TOP-2 picks
// per reduction round. Butterfly keeps the two smallest keys (merge of sorted
// pairs per level). Pick2 (q2,t2) is valid iff q2 != q1: t2 != t1 is
// structural (candidates are distinct columns), and when q2 != q1 every stale
// column's stored value >= kb bounds its true new min from below, so kb is
// provably the reference's next pick. Tie-break = jnp.argmin flat order via
// key ordf(v)<<32 | q<<7 | t.
// ---------------------------------------------------------------------------
__global__ __launch_bounds__(64) void hm_greedy_col2(
    const float* __restrict__ cost,     // [B,Q,T]
    const float* __restrict__ cm_ws,    // [B*T]
    const int*   __restrict__ ca_ws,    // [B*T]
    float* __restrict__ out_src,        // [B,N]
    float* __restrict__ out_tgt)        // [B,N]
{
    int b = blockIdx.x;
    int l = threadIdx.x;                // 0..63
    const float* Cb = cost + (size_t)b * Q_ * T_;

    int   t0 = l, t1 = 64 + l;
    bool  act0 = true;
    bool  act1 = (t1 < T_);
    float cmin0 = cm_ws[b * T_ + t0];
    int   carg0 = ca_ws[b * T_ + t0];
    float cmin1 = act1 ? cm_ws[b * T_ + t1] : BIGF;
    int   carg1 = act1 ? ca_ws[b * T_ + t1] : 0;

    unsigned removed = 0u;  // bit i => row (l + 64*i) removed

    int k = 0;
    while (k < N_) {
        // ---- per-lane sorted pair of candidate keys
        ull k0 = act0 ? (((ull)hm_ordf(cmin0) << 32) |
                         ((unsigned)carg0 << 7) | (unsigned)t0) : ~0ull;
        ull k1 = act1 ? (((ull)hm_ordf(cmin1) << 32) |
                         ((unsigned)carg1 << 7) | (unsigned)t1) : ~0ull;
        ull ka = (k0 < k1) ? k0 : k1;
        ull kb = (k0 < k1) ? k1 : k0;

        // ---- butterfly: wave-wide top-2 (merge two sorted pairs per level)
#pragma unroll
        for (int off = 32; off >= 1; off >>= 1) {
            ull pa = __shfl_xor(ka, off, 64);
            ull pb = __shfl_xor(kb, off, 64);
            ull na  = (ka < pa) ? ka : pa;
            ull mx  = (ka < pa) ? pa : ka;
            ull mn2 = (kb < pb) ? kb : pb;
            kb = (mx < mn2) ? mx : mn2;
            ka = na;
        }

        int q1  = (int)((ka >> 7) & 1023);
        int tt1 = (int)(ka & 127);
        int q2  = (int)((kb >> 7) & 1023);
        int tt2 = (int)(kb & 127);
        bool dbl = (k + 1 < N_) && (q2 != q1) && (kb != ~0ull);

        if (l == 0) {
            out_src[b * N_ + k] = (float)q1;
            out_tgt[b * N_ + k] = (float)tt1;
            if (dbl) {
                out_src[b * N_ + k + 1] = (float)q2;
                out_tgt[b * N_ + k + 1] = (float)tt2;
            }
        }

        // ---- deactivate picked columns, mark removed rows
        if (t0 == tt1 || (dbl && t0 == tt2)) act0 = false;
        if (t1 == tt1 || (dbl && t1 == tt2)) act1 = false;
        if ((q1 & 63) == l) removed |= 1u << (q1 >> 6);
        if (dbl && (q2 & 63) == l) removed |= 1u << (q2 >> 6);

        // ---- rescan columns whose cached argmin row just died
        bool h0 = act0 && (carg0 == q1 || (dbl && carg0 == q2));
        bool h1 = act1 && (carg1 == q1 || (dbl && carg1 == q2));
        ull bal0 = __ballot(h0);
        ull bal1 = __ballot(h1);

        while (bal0 | bal1) {
            int tc, owner_entry, owner_lane;
            if (bal0) {
                int p = __ffsll(bal0) - 1;
                bal0 &= bal0 - 1;
                tc = p; owner_entry = 0; owner_lane = p;
            } else {
                int p = __ffsll(bal1) - 1;
                bal1 &= bal1 - 1;
                tc = 64 + p; owner_entry = 1; owner_lane = p;
            }
            ull bk = ~0ull;
#pragma unroll
            for (int i = 0; i < ROWS_PER_LANE; ++i) {
                int r = l + 64 * i;
                bool ok = (r < Q_) && !((removed >> i) & 1u);
                float v = ok ? Cb[(size_t)r * T_ + tc] : BIGF;
                ull kk = ((ull)hm_ordf(v) << 32) | (unsigned)r;
                bk = (kk < bk) ? kk : bk;
            }
#pragma unroll
            for (int off = 32; off >= 1; off >>= 1) {
                ull o = __shfl_xor(bk, off, 64);
                bk = (o < bk) ? o : bk;
            }
            float nv = hm_unordf((unsigned int)(bk >> 32));
            int   nr = (int)(bk & 1023u);
            if (owner_entry == 0) {
                if (l == owner_lane) { cmin0 = nv; carg0 = nr; }
            } else {
                if (l == owner_lane) { cmin1 = nv; carg1 = nr; }
            }
        }

        k += dbl ? 2 : 1;
    }
}

// ---------------------------------------------------------------------------
extern "C" void kernel_launch(void* const* d_in, const int* in_sizes, int n_in,
                              void* d_out, int out_size, void* d_ws, size_t ws_size,
                              hipStream_t stream)
{
    const float* pred_logits = (const float*)d_in[0];  // [B,Q,C]
    const float* pred_boxes  = (const float*)d_in[1];  // [B,Q,4]
    const int*   tgt_labels  = (const int*)d_in[2];    // [B,T]
    const float* tgt_boxes   = (const float*)d_in[3];  // [B,T,4]

    float* out_cost = (float*)d_out;                       // [B,Q,T]
    float* out_src  = out_cost + (size_t)B_ * Q_ * T_;     // [B,N]
    float* out_tgt  = out_src  + (size_t)B_ * N_;          // [B,N]

    // workspace layout
    float* cm_ws = (float*)d_ws;                           // [B*T] f32
    int*   ca_ws = (int*)(cm_ws + (size_t)B_ * T_);        // [B*T] i32

    // 1: fused softmax + cost — one wave per (b,q)
    {
        int waves  = B_ * Q_;                  // 57600
        int blocks = waves / 4;                // 256 threads = 4 waves/block
        hm_cost_fused<<<blocks, 256, 0, stream>>>(pred_logits, pred_boxes,
                                                  tgt_labels, tgt_boxes, out_cost);
    }
    // 2: initial column minima — one wave per (b,t)
    {
        int waves  = B_ * T_;                  // 6400
        int blocks = (waves * 64 + 255) / 256; // 1600
        hm_colmin_wave<<<blocks, 256, 0, stream>>>(out_cost, cm_ws, ca_ws);
    }
    // 3: greedy assignment — one wave per batch, top-2 per round
    hm_greedy_col2<<<B_, 64, 0, stream>>>(out_cost, cm_ws, ca_ws, out_src, out_tgt);
}